// Round 9
// baseline (404.418 us; speedup 1.0000x reference)
//
#include <hip/hip_runtime.h>
#include <hip/hip_bf16.h>

#define N_NODES 100000
#define N_EDGES 1600000
#define SCAN_BLOCKS 391          // ceil(100000/256)
#define FILL_RANGES 8            // one node-range per XCD (L2 locality)
#define FILL_CHUNKS 200          // edge chunks per range
#define FILL_CH (N_EDGES / FILL_CHUNKS)   // 8000 edges/chunk
#define RANGE_N (N_NODES / FILL_RANGES)   // 12500 nodes/range

// Float tensors are genuine fp32 (confirmed R3-vs-R5). Internal compute bf16
// via MFMA; output fp32.

typedef __hip_bfloat16 bf16;
typedef short short8 __attribute__((ext_vector_type(8)));
typedef float f32x4 __attribute__((ext_vector_type(4)));
typedef unsigned int uint;

__device__ __forceinline__ short f2bs(float f) {
    bf16 h = __float2bfloat16(f);
    short s; __builtin_memcpy(&s, &h, 2); return s;
}
__device__ __forceinline__ float lo_bf(uint w) {
    uint v = w << 16; float f; __builtin_memcpy(&f, &v, 4); return f;
}
__device__ __forceinline__ float hi_bf(uint w) {
    uint v = w & 0xFFFF0000u; float f; __builtin_memcpy(&f, &v, 4); return f;
}
__device__ __forceinline__ uint pack2(float a, float b) {
    return (uint)(unsigned short)f2bs(a) | ((uint)(unsigned short)f2bs(b) << 16);
}

// 8 consecutive fp32 -> bf16 bits (two float4 loads)
__device__ __forceinline__ short8 cvt8(const float* __restrict__ p) {
    float4 v0 = *(const float4*)p;
    float4 v1 = *(const float4*)(p + 4);
    short8 t;
    t[0] = f2bs(v0.x); t[1] = f2bs(v0.y); t[2] = f2bs(v0.z); t[3] = f2bs(v0.w);
    t[4] = f2bs(v1.x); t[5] = f2bs(v1.y); t[6] = f2bs(v1.z); t[7] = f2bs(v1.w);
    return t;
}
// 8 consecutive bf16 (16B vector load)
__device__ __forceinline__ short8 load8bf(const bf16* __restrict__ p, long idx) {
    return *(const short8*)((const short*)p + idx);
}

// ---- x -> bf16 conversion --------------------------------------------
__global__ __launch_bounds__(256) void convert_kernel(
    const float* __restrict__ in, bf16* __restrict__ out)
{
    int i = blockIdx.x * 256 + threadIdx.x;      // 1.6M threads x 4 elems
    float4 v = ((const float4*)in)[i];
    uint2 o;
    o.x = pack2(v.x, v.y);
    o.y = pack2(v.z, v.w);
    ((uint2*)out)[i] = o;
}

// ---- CSR build --------------------------------------------------------
__global__ __launch_bounds__(256) void hist_kernel(
    const int* __restrict__ dst, int* __restrict__ deg)
{
    int e = blockIdx.x * 256 + threadIdx.x;
    if (e < N_EDGES) atomicAdd(&deg[dst[e]], 1);
}

__global__ __launch_bounds__(256) void scan1_kernel(
    const int* __restrict__ deg, int* __restrict__ offs, int* __restrict__ bsum)
{
    __shared__ int tmp[256];
    int t = threadIdx.x;
    int i = blockIdx.x * 256 + t;
    int v = (i < N_NODES) ? deg[i] : 0;
    tmp[t] = v;
    __syncthreads();
#pragma unroll
    for (int off = 1; off < 256; off <<= 1) {
        int add = (t >= off) ? tmp[t - off] : 0;
        __syncthreads();
        tmp[t] += add;
        __syncthreads();
    }
    if (i < N_NODES) offs[i] = tmp[t] - v;          // exclusive
    if (t == 255) bsum[blockIdx.x] = tmp[255];
}

__global__ __launch_bounds__(512) void scan2_kernel(int* __restrict__ bsum)
{
    __shared__ int tmp[512];
    int t = threadIdx.x;
    int v = (t < SCAN_BLOCKS) ? bsum[t] : 0;
    tmp[t] = v;
    __syncthreads();
#pragma unroll
    for (int off = 1; off < 512; off <<= 1) {
        int add = (t >= off) ? tmp[t - off] : 0;
        __syncthreads();
        tmp[t] += add;
        __syncthreads();
    }
    if (t < SCAN_BLOCKS) bsum[t] = tmp[t] - v;      // exclusive
}

__global__ __launch_bounds__(256) void scan3_kernel(
    int* __restrict__ offs, int* __restrict__ woff, const int* __restrict__ bsum)
{
    int i = blockIdx.x * 256 + threadIdx.x;
    if (i < N_NODES) {
        int v = offs[i] + bsum[blockIdx.x];
        offs[i] = v;
        woff[i] = v;
    }
    if (i == 0) offs[N_NODES] = N_EDGES;
}

// XCD-localized fill: block b -> node range (b&7), edge chunk (b>>3).
// dst scanned as int4 (4x fewer fetch instructions); src loaded only on match.
__global__ __launch_bounds__(256) void fill_kernel(
    const int* __restrict__ src, const int* __restrict__ dst,
    int* __restrict__ woff, int* __restrict__ csr)
{
    int r = blockIdx.x & (FILL_RANGES - 1);
    int c = blockIdx.x >> 3;
    int lo = r * RANGE_N, hi = lo + RANGE_N;
    const int4* dst4 = (const int4*)(dst + c * FILL_CH);
    int e0 = c * FILL_CH;
    for (int i = threadIdx.x; i < FILL_CH / 4; i += 256) {
        int4 d4 = dst4[i];
        int e = e0 + i * 4;
#pragma unroll
        for (int k = 0; k < 4; k++) {
            int d = (&d4.x)[k];
            if (d >= lo && d < hi) {
                int pos = atomicAdd(&woff[d], 1);
                csr[pos] = src[e + k];
            }
        }
    }
}

// ---- Mean aggregation (gather, bf16 source) ---------------------------
// One wave per node. Lane j: row-slot ri=j>>3, 16B feature chunk ci=j&7.
// Each iteration gathers 8 rows in flight (one dwordx4 per lane = full
// 128B row across 8 lanes). 3-step shfl_xor (8/16/32) reduces row-slots,
// then lanes ri==0 write the mean row as a coalesced 128B store.
__global__ __launch_bounds__(256) void aggregate_mean(
    const bf16* __restrict__ feat, const int* __restrict__ offs,
    const int* __restrict__ csr, bf16* __restrict__ mean)
{
    int wave = threadIdx.x >> 6, lane = threadIdx.x & 63;
    int ri = lane >> 3, ci = lane & 7;
    int n = blockIdx.x * 4 + wave;
    if (n >= N_NODES) return;
    int beg = offs[n], end = offs[n + 1];
    float acc[8] = {0.f, 0.f, 0.f, 0.f, 0.f, 0.f, 0.f, 0.f};
    for (int i = beg + ri; i < end; i += 8) {
        int s = csr[i];
        uint4 w = *(const uint4*)((const uint*)feat + (long)s * 32 + ci * 4);
        acc[0] += lo_bf(w.x); acc[1] += hi_bf(w.x);
        acc[2] += lo_bf(w.y); acc[3] += hi_bf(w.y);
        acc[4] += lo_bf(w.z); acc[5] += hi_bf(w.z);
        acc[6] += lo_bf(w.w); acc[7] += hi_bf(w.w);
    }
#pragma unroll
    for (int m = 8; m < 64; m <<= 1) {
#pragma unroll
        for (int k = 0; k < 8; k++) acc[k] += __shfl_xor(acc[k], m);
    }
    if (ri == 0) {
        int d = end - beg;
        float inv = d > 0 ? 1.0f / (float)d : 0.0f;
        short8 st;
#pragma unroll
        for (int k = 0; k < 8; k++) st[k] = f2bs(acc[k] * inv);
        *(short8*)((short*)mean + (long)n * 64 + ci * 8) = st;
    }
}

// ---- MFMA node layers -------------------------------------------------
// C[node][f] = relu( mean[node]·Wl[f] + self[node]·Wr[f] + bias[f] )
// K=128 GEMM: A = [mean || self], B = [Wl ; Wr].
// mfma_f32_16x16x32_bf16: A: m=lane&15, k(chunk c) = c*32 + quad*8 + j
// C/D: col=lane&15 (=f), row=quad*4+reg (=node). 16 nodes/wave, 16 MFMA.

__device__ __forceinline__ void load_afrags(
    short8* a, const bf16* __restrict__ mean,
    const bf16* __restrict__ self, int na, int quad)
{
#pragma unroll
    for (int c = 0; c < 2; c++)             // mean part, k = 0..63
        a[c] = load8bf(mean, (long)na * 64 + c * 32 + quad * 8);
#pragma unroll
    for (int c = 0; c < 2; c++)             // self part, k = 64..127
        a[2 + c] = load8bf(self, (long)na * 64 + c * 32 + quad * 8);
}

__device__ __forceinline__ short8 load_bfrag(
    const float* __restrict__ Wl, const float* __restrict__ Wr,
    int f, int c, int quad)
{
    if (c < 2) return cvt8(Wl + (long)f * 64 + c * 32 + quad * 8);
    return cvt8(Wr + (long)f * 64 + (c - 2) * 32 + quad * 8);
}

// Layer 1: writes h1 (bf16). self = xb (pre-converted x).
__global__ __launch_bounds__(256) void node_layer1_mfma(
    const bf16* __restrict__ xb, const bf16* __restrict__ mean,
    const float* __restrict__ Wl, const float* __restrict__ bl,
    const float* __restrict__ Wr, bf16* __restrict__ h_out)
{
    int tid = threadIdx.x;
    int wave = tid >> 6, lane = tid & 63;
    int quad = lane >> 4, n16 = lane & 15;
    int nb = (blockIdx.x * 4 + wave) * 16;

    int node_a = nb + n16;
    int na = node_a < N_NODES ? node_a : N_NODES - 1;
    short8 a[4];
    load_afrags(a, mean, xb, na, quad);

#pragma unroll
    for (int t = 0; t < 4; t++) {
        int f = 16 * t + n16;
        f32x4 acc = {0.f, 0.f, 0.f, 0.f};
#pragma unroll
        for (int c = 0; c < 4; c++) {
            short8 b = load_bfrag(Wl, Wr, f, c, quad);
            acc = __builtin_amdgcn_mfma_f32_16x16x32_bf16(a[c], b, acc, 0, 0, 0);
        }
        float bias = bl[f];
#pragma unroll
        for (int r = 0; r < 4; r++) {
            int node = nb + quad * 4 + r;
            if (node < N_NODES)
                h_out[(long)node * 64 + f] = __float2bfloat16(fmaxf(acc[r] + bias, 0.0f));
        }
    }
}

// Layer 2 fused with edge-scorer projection; h2 never materialized.
__global__ __launch_bounds__(256) void node_layer2_mfma(
    const bf16* __restrict__ h1, const bf16* __restrict__ mean,
    const float* __restrict__ Wl, const float* __restrict__ bl,
    const float* __restrict__ Wr, const float* __restrict__ Wlin,
    float* __restrict__ s_src, float* __restrict__ s_dst)
{
    int tid = threadIdx.x;
    int wave = tid >> 6, lane = tid & 63;
    int quad = lane >> 4, n16 = lane & 15;
    int nb = (blockIdx.x * 4 + wave) * 16;

    int node_a = nb + n16;
    int na = node_a < N_NODES ? node_a : N_NODES - 1;
    short8 a[4];
    load_afrags(a, mean, h1, na, quad);

    float sa[4] = {0.f, 0.f, 0.f, 0.f};
    float sb[4] = {0.f, 0.f, 0.f, 0.f};
#pragma unroll
    for (int t = 0; t < 4; t++) {
        int f = 16 * t + n16;
        f32x4 acc = {0.f, 0.f, 0.f, 0.f};
#pragma unroll
        for (int c = 0; c < 4; c++) {
            short8 b = load_bfrag(Wl, Wr, f, c, quad);
            acc = __builtin_amdgcn_mfma_f32_16x16x32_bf16(a[c], b, acc, 0, 0, 0);
        }
        float bias = bl[f];
        float wa = Wlin[f];
        float wb = Wlin[64 + f];
#pragma unroll
        for (int r = 0; r < 4; r++) {
            float h = fmaxf(acc[r] + bias, 0.0f);
            sa[r] += h * wa;
            sb[r] += h * wb;
        }
    }
#pragma unroll
    for (int m = 1; m < 16; m <<= 1) {
#pragma unroll
        for (int r = 0; r < 4; r++) {
            sa[r] += __shfl_xor(sa[r], m);
            sb[r] += __shfl_xor(sb[r], m);
        }
    }
    if (n16 == 0) {
#pragma unroll
        for (int r = 0; r < 4; r++) {
            int node = nb + quad * 4 + r;
            if (node < N_NODES) { s_src[node] = sa[r]; s_dst[node] = sb[r]; }
        }
    }
}

// 4 edges per thread (int4 index loads, float4 output store).
__global__ __launch_bounds__(256) void edge_out_kernel(
    const int* __restrict__ src, const int* __restrict__ dst,
    const float* __restrict__ s_src, const float* __restrict__ s_dst,
    const float* __restrict__ blin, float* __restrict__ out)
{
    int i = blockIdx.x * 256 + threadIdx.x;
    if (i >= N_EDGES / 4) return;
    int4 s4 = ((const int4*)src)[i];
    int4 d4 = ((const int4*)dst)[i];
    float b = blin[0];
    float4 o;
    o.x = s_src[s4.x] + s_dst[d4.x] + b;
    o.y = s_src[s4.y] + s_dst[d4.y] + b;
    o.z = s_src[s4.z] + s_dst[d4.z] + b;
    o.w = s_src[s4.w] + s_dst[d4.w] + b;
    ((float4*)out)[i] = o;
}

extern "C" void kernel_launch(void* const* d_in, const int* in_sizes, int n_in,
                              void* d_out, int out_size, void* d_ws, size_t ws_size,
                              hipStream_t stream) {
    const float* x    = (const float*)d_in[0];
    const int*   ei   = (const int*)d_in[1];
    const float* W1l  = (const float*)d_in[2];
    const float* b1l  = (const float*)d_in[3];
    const float* W1r  = (const float*)d_in[4];
    const float* W2l  = (const float*)d_in[5];
    const float* b2l  = (const float*)d_in[6];
    const float* W2r  = (const float*)d_in[7];
    const float* Wlin = (const float*)d_in[8];
    const float* blin = (const float*)d_in[9];
    float* out = (float*)d_out;

    const int* src = ei;
    const int* dst = ei + N_EDGES;

    // Workspace (~46.8 MB)
    char* w = (char*)d_ws;
    bf16*  xb   = (bf16*)w;  w += (size_t)N_NODES * 64 * 2;   // 12.8 MB
    bf16*  mean = (bf16*)w;  w += (size_t)N_NODES * 64 * 2;   // 12.8 MB (reused)
    bf16*  h1   = (bf16*)w;  w += (size_t)N_NODES * 64 * 2;   // 12.8 MB
    float* ssrc = (float*)w; w += (size_t)N_NODES * 4;
    float* sdst = (float*)w; w += (size_t)N_NODES * 4;
    int*   deg  = (int*)w;   w += (size_t)N_NODES * 4;
    int*   offs = (int*)w;   w += (size_t)(N_NODES + 4) * 4;
    int*   woff = (int*)w;   w += (size_t)N_NODES * 4;
    int*   bsum = (int*)w;   w += 4096;
    int*   csr  = (int*)w;   w += (size_t)N_EDGES * 4;        // 6.4 MB

    const int edge_blocks = (N_EDGES + 255) / 256;   // 6250
    const int conv_blocks = (N_NODES * 64 / 4) / 256;// 6250
    const int agg_blocks  = (N_NODES + 3) / 4;       // 25000
    const int node_blocks = (N_NODES + 63) / 64;     // 1563
    const int eo_blocks   = (N_EDGES / 4 + 255) / 256; // 1563

    // ---- x -> bf16 + CSR build ----
    convert_kernel<<<conv_blocks, 256, 0, stream>>>(x, xb);
    (void)hipMemsetAsync(deg, 0, (size_t)N_NODES * 4, stream);
    hist_kernel<<<edge_blocks, 256, 0, stream>>>(dst, deg);
    scan1_kernel<<<SCAN_BLOCKS, 256, 0, stream>>>(deg, offs, bsum);
    scan2_kernel<<<1, 512, 0, stream>>>(bsum);
    scan3_kernel<<<SCAN_BLOCKS, 256, 0, stream>>>(offs, woff, bsum);
    fill_kernel<<<FILL_RANGES * FILL_CHUNKS, 256, 0, stream>>>(src, dst, woff, csr);

    // ---- Layer 1 ----
    aggregate_mean<<<agg_blocks, 256, 0, stream>>>(xb, offs, csr, mean);
    node_layer1_mfma<<<node_blocks, 256, 0, stream>>>(xb, mean, W1l, b1l, W1r, h1);

    // ---- Layer 2 (mean buffer reused) ----
    aggregate_mean<<<agg_blocks, 256, 0, stream>>>(h1, offs, csr, mean);
    node_layer2_mfma<<<node_blocks, 256, 0, stream>>>(h1, mean, W2l, b2l, W2r, Wlin, ssrc, sdst);

    // ---- Edge scores ----
    edge_out_kernel<<<eo_blocks, 256, 0, stream>>>(src, dst, ssrc, sdst, blin, out);
}

// Round 10
// 314.612 us; speedup vs baseline: 1.2855x; 1.2855x over previous
//
#include <hip/hip_runtime.h>
#include <hip/hip_bf16.h>

#define N_NODES 100000
#define N_EDGES 1600000
#define NBUCK 196                 // ceil(100000/512) node buckets (512 nodes each)
#define CHUNK 8192                // edges per partition block
#define PART_BLOCKS 196           // ceil(1600000/8192)
#define BCAP 12288                // LDS csr capacity per bucket (avg 8192, +45 sigma)

// Float tensors are genuine fp32 (confirmed R3-vs-R5). Internal compute bf16
// via MFMA; output fp32.

typedef __hip_bfloat16 bf16;
typedef short short8 __attribute__((ext_vector_type(8)));
typedef float f32x4 __attribute__((ext_vector_type(4)));
typedef unsigned int uint;

__device__ __forceinline__ short f2bs(float f) {
    bf16 h = __float2bfloat16(f);
    short s; __builtin_memcpy(&s, &h, 2); return s;
}
__device__ __forceinline__ float lo_bf(uint w) {
    uint v = w << 16; float f; __builtin_memcpy(&f, &v, 4); return f;
}
__device__ __forceinline__ float hi_bf(uint w) {
    uint v = w & 0xFFFF0000u; float f; __builtin_memcpy(&f, &v, 4); return f;
}
__device__ __forceinline__ uint pack2(float a, float b) {
    return (uint)(unsigned short)f2bs(a) | ((uint)(unsigned short)f2bs(b) << 16);
}
__device__ __forceinline__ short8 cvt8(const float* __restrict__ p) {
    float4 v0 = *(const float4*)p;
    float4 v1 = *(const float4*)(p + 4);
    short8 t;
    t[0] = f2bs(v0.x); t[1] = f2bs(v0.y); t[2] = f2bs(v0.z); t[3] = f2bs(v0.w);
    t[4] = f2bs(v1.x); t[5] = f2bs(v1.y); t[6] = f2bs(v1.z); t[7] = f2bs(v1.w);
    return t;
}
__device__ __forceinline__ short8 load8bf(const bf16* __restrict__ p, long idx) {
    return *(const short8*)((const short*)p + idx);
}

// ---- x -> bf16 conversion --------------------------------------------
__global__ __launch_bounds__(256) void convert_kernel(
    const float* __restrict__ in, bf16* __restrict__ out)
{
    int i = blockIdx.x * 256 + threadIdx.x;      // 1.6M threads x 4 elems
    float4 v = ((const float4*)in)[i];
    uint2 o;
    o.x = pack2(v.x, v.y);
    o.y = pack2(v.z, v.w);
    ((uint2*)out)[i] = o;
}

// ---- Bucketed CSR build ----------------------------------------------
// Bucket b = dst >> 9 (512 nodes per bucket). Payload packs src (17b) and
// local dst (9b) into one int. All global writes are coalesced runs;
// this replaces hist/scan/fill whose random 4B scatter cost 74MB writeback (R8/R9).

// A1: coarse 256-bucket histogram (LDS-staged)
__global__ __launch_bounds__(256) void bucket_hist(
    const int* __restrict__ dst, int* __restrict__ bhist)
{
    __shared__ int h[256];
    int t = threadIdx.x;
    h[t] = 0;
    __syncthreads();
    int e0 = blockIdx.x * CHUNK;
    for (int i = t; i < CHUNK; i += 256) {
        int e = e0 + i;
        if (e < N_EDGES) atomicAdd(&h[dst[e] >> 9], 1);
    }
    __syncthreads();
    if (h[t]) atomicAdd(&bhist[t], h[t]);
}

// A2: exclusive scan of 256 bucket counts -> bases + cursors
__global__ __launch_bounds__(256) void bucket_scan(
    const int* __restrict__ bhist, int* __restrict__ bases, int* __restrict__ gcur)
{
    __shared__ int tmp[256];
    int t = threadIdx.x;
    int v = bhist[t];
    tmp[t] = v;
    __syncthreads();
#pragma unroll
    for (int off = 1; off < 256; off <<= 1) {
        int add = (t >= off) ? tmp[t - off] : 0;
        __syncthreads();
        tmp[t] += add;
        __syncthreads();
    }
    int excl = tmp[t] - v;
    bases[t] = excl;
    gcur[t] = excl;
    if (t == 0) bases[256] = N_EDGES;
}

// A3: partition edges into bucket-contiguous pk[] with LDS staging.
// Per block: LDS hist -> scan -> scatter -> per-bucket coalesced flush.
__global__ __launch_bounds__(256) void partition_kernel(
    const int* __restrict__ src, const int* __restrict__ dst,
    int* __restrict__ gcur, int* __restrict__ pk)
{
    __shared__ int h[256], scn[256], cur[256], gb[256];
    __shared__ int pl[CHUNK];
    __shared__ unsigned char bb[CHUNK];
    int t = threadIdx.x;
    h[t] = 0;
    __syncthreads();
    int e0 = blockIdx.x * CHUNK;
    // pass 1: histogram
    for (int i = t; i < CHUNK; i += 256) {
        int e = e0 + i;
        if (e < N_EDGES) atomicAdd(&h[dst[e] >> 9], 1);
    }
    __syncthreads();
    // scan (inclusive Hillis-Steele)
    scn[t] = h[t];
    __syncthreads();
#pragma unroll
    for (int off = 1; off < 256; off <<= 1) {
        int add = (t >= off) ? scn[t - off] : 0;
        __syncthreads();
        scn[t] += add;
        __syncthreads();
    }
    int excl = scn[t] - h[t];
    cur[t] = excl;
    __syncthreads();
    int cnt_local = scn[255];
    // pass 2: scatter into LDS (bucket-sorted)
    for (int i = t; i < CHUNK; i += 256) {
        int e = e0 + i;
        if (e < N_EDGES) {
            int d = dst[e];
            int b = d >> 9;
            int p = atomicAdd(&cur[b], 1);
            pl[p] = src[e] | ((d & 511) << 17);
            bb[p] = (unsigned char)b;
        }
    }
    __syncthreads();
    // reserve global space per bucket
    if (h[t] > 0) gb[t] = atomicAdd(&gcur[t], h[t]);
    __syncthreads();
    // flush: position i of bucket b goes to gb[b] + (i - excl[b])
    for (int i = t; i < cnt_local; i += 256) {
        int b = bb[i];
        pk[gb[b] + (i - (scn[b] - h[b]))] = pl[i];
    }
}

// B: build csr + offs within each bucket; all global writes sequential.
__global__ __launch_bounds__(512) void csr_build(
    const int* __restrict__ bases, const int* __restrict__ pk,
    int* __restrict__ csr, int* __restrict__ offs)
{
    __shared__ int deg[512], scn[512], cur[512];
    __shared__ int csr_l[BCAP];
    int t = threadIdx.x;
    int b = blockIdx.x;
    int base = bases[b], cnt = bases[b + 1] - base;
    int node0 = b << 9;
    deg[t] = 0;
    __syncthreads();
    for (int i = t; i < cnt; i += 512)
        atomicAdd(&deg[pk[base + i] >> 17], 1);
    __syncthreads();
    scn[t] = deg[t];
    __syncthreads();
#pragma unroll
    for (int off = 1; off < 512; off <<= 1) {
        int add = (t >= off) ? scn[t - off] : 0;
        __syncthreads();
        scn[t] += add;
        __syncthreads();
    }
    int excl = scn[t] - deg[t];
    cur[t] = excl;
    int n = node0 + t;
    if (n < N_NODES) offs[n] = base + excl;
    if (b == NBUCK - 1 && t == 0) offs[N_NODES] = N_EDGES;
    __syncthreads();
    if (cnt <= BCAP) {
        for (int i = t; i < cnt; i += 512) {
            int v = pk[base + i];
            int p = atomicAdd(&cur[v >> 17], 1);
            csr_l[p] = v & 0x1FFFF;
        }
        __syncthreads();
        for (int i = t; i < cnt; i += 512)
            csr[base + i] = csr_l[i];
    } else {
        // overflow fallback (never expected: cnt avg 8192, cap 12288)
        for (int i = t; i < cnt; i += 512) {
            int v = pk[base + i];
            int p = atomicAdd(&cur[v >> 17], 1);
            csr[base + p] = v & 0x1FFFF;
        }
    }
}

// ---- Mean aggregation (gather, bf16 source) ---------------------------
// One wave per node. Lane j: row-slot ri=j>>3, 16B feature chunk ci=j&7.
// 8 rows in flight; 3-step shfl_xor reduces row-slots; coalesced 128B store.
__global__ __launch_bounds__(256) void aggregate_mean(
    const bf16* __restrict__ feat, const int* __restrict__ offs,
    const int* __restrict__ csr, bf16* __restrict__ mean)
{
    int wave = threadIdx.x >> 6, lane = threadIdx.x & 63;
    int ri = lane >> 3, ci = lane & 7;
    int n = blockIdx.x * 4 + wave;
    if (n >= N_NODES) return;
    int beg = offs[n], end = offs[n + 1];
    float acc[8] = {0.f, 0.f, 0.f, 0.f, 0.f, 0.f, 0.f, 0.f};
    for (int i = beg + ri; i < end; i += 8) {
        int s = csr[i];
        uint4 w = *(const uint4*)((const uint*)feat + (long)s * 32 + ci * 4);
        acc[0] += lo_bf(w.x); acc[1] += hi_bf(w.x);
        acc[2] += lo_bf(w.y); acc[3] += hi_bf(w.y);
        acc[4] += lo_bf(w.z); acc[5] += hi_bf(w.z);
        acc[6] += lo_bf(w.w); acc[7] += hi_bf(w.w);
    }
#pragma unroll
    for (int m = 8; m < 64; m <<= 1) {
#pragma unroll
        for (int k = 0; k < 8; k++) acc[k] += __shfl_xor(acc[k], m);
    }
    if (ri == 0) {
        int d = end - beg;
        float inv = d > 0 ? 1.0f / (float)d : 0.0f;
        short8 st;
#pragma unroll
        for (int k = 0; k < 8; k++) st[k] = f2bs(acc[k] * inv);
        *(short8*)((short*)mean + (long)n * 64 + ci * 8) = st;
    }
}

// ---- MFMA node layers (verified R6) -----------------------------------
__device__ __forceinline__ void load_afrags(
    short8* a, const bf16* __restrict__ mean,
    const bf16* __restrict__ self, int na, int quad)
{
#pragma unroll
    for (int c = 0; c < 2; c++)
        a[c] = load8bf(mean, (long)na * 64 + c * 32 + quad * 8);
#pragma unroll
    for (int c = 0; c < 2; c++)
        a[2 + c] = load8bf(self, (long)na * 64 + c * 32 + quad * 8);
}

__device__ __forceinline__ short8 load_bfrag(
    const float* __restrict__ Wl, const float* __restrict__ Wr,
    int f, int c, int quad)
{
    if (c < 2) return cvt8(Wl + (long)f * 64 + c * 32 + quad * 8);
    return cvt8(Wr + (long)f * 64 + (c - 2) * 32 + quad * 8);
}

__global__ __launch_bounds__(256) void node_layer1_mfma(
    const bf16* __restrict__ xb, const bf16* __restrict__ mean,
    const float* __restrict__ Wl, const float* __restrict__ bl,
    const float* __restrict__ Wr, bf16* __restrict__ h_out)
{
    int tid = threadIdx.x;
    int wave = tid >> 6, lane = tid & 63;
    int quad = lane >> 4, n16 = lane & 15;
    int nb = (blockIdx.x * 4 + wave) * 16;

    int node_a = nb + n16;
    int na = node_a < N_NODES ? node_a : N_NODES - 1;
    short8 a[4];
    load_afrags(a, mean, xb, na, quad);

#pragma unroll
    for (int t = 0; t < 4; t++) {
        int f = 16 * t + n16;
        f32x4 acc = {0.f, 0.f, 0.f, 0.f};
#pragma unroll
        for (int c = 0; c < 4; c++) {
            short8 b = load_bfrag(Wl, Wr, f, c, quad);
            acc = __builtin_amdgcn_mfma_f32_16x16x32_bf16(a[c], b, acc, 0, 0, 0);
        }
        float bias = bl[f];
#pragma unroll
        for (int r = 0; r < 4; r++) {
            int node = nb + quad * 4 + r;
            if (node < N_NODES)
                h_out[(long)node * 64 + f] = __float2bfloat16(fmaxf(acc[r] + bias, 0.0f));
        }
    }
}

__global__ __launch_bounds__(256) void node_layer2_mfma(
    const bf16* __restrict__ h1, const bf16* __restrict__ mean,
    const float* __restrict__ Wl, const float* __restrict__ bl,
    const float* __restrict__ Wr, const float* __restrict__ Wlin,
    float* __restrict__ s_src, float* __restrict__ s_dst)
{
    int tid = threadIdx.x;
    int wave = tid >> 6, lane = tid & 63;
    int quad = lane >> 4, n16 = lane & 15;
    int nb = (blockIdx.x * 4 + wave) * 16;

    int node_a = nb + n16;
    int na = node_a < N_NODES ? node_a : N_NODES - 1;
    short8 a[4];
    load_afrags(a, mean, h1, na, quad);

    float sa[4] = {0.f, 0.f, 0.f, 0.f};
    float sb[4] = {0.f, 0.f, 0.f, 0.f};
#pragma unroll
    for (int t = 0; t < 4; t++) {
        int f = 16 * t + n16;
        f32x4 acc = {0.f, 0.f, 0.f, 0.f};
#pragma unroll
        for (int c = 0; c < 4; c++) {
            short8 b = load_bfrag(Wl, Wr, f, c, quad);
            acc = __builtin_amdgcn_mfma_f32_16x16x32_bf16(a[c], b, acc, 0, 0, 0);
        }
        float bias = bl[f];
        float wa = Wlin[f];
        float wb = Wlin[64 + f];
#pragma unroll
        for (int r = 0; r < 4; r++) {
            float h = fmaxf(acc[r] + bias, 0.0f);
            sa[r] += h * wa;
            sb[r] += h * wb;
        }
    }
#pragma unroll
    for (int m = 1; m < 16; m <<= 1) {
#pragma unroll
        for (int r = 0; r < 4; r++) {
            sa[r] += __shfl_xor(sa[r], m);
            sb[r] += __shfl_xor(sb[r], m);
        }
    }
    if (n16 == 0) {
#pragma unroll
        for (int r = 0; r < 4; r++) {
            int node = nb + quad * 4 + r;
            if (node < N_NODES) { s_src[node] = sa[r]; s_dst[node] = sb[r]; }
        }
    }
}

__global__ __launch_bounds__(256) void edge_out_kernel(
    const int* __restrict__ src, const int* __restrict__ dst,
    const float* __restrict__ s_src, const float* __restrict__ s_dst,
    const float* __restrict__ blin, float* __restrict__ out)
{
    int i = blockIdx.x * 256 + threadIdx.x;
    if (i >= N_EDGES / 4) return;
    int4 s4 = ((const int4*)src)[i];
    int4 d4 = ((const int4*)dst)[i];
    float b = blin[0];
    float4 o;
    o.x = s_src[s4.x] + s_dst[d4.x] + b;
    o.y = s_src[s4.y] + s_dst[d4.y] + b;
    o.z = s_src[s4.z] + s_dst[d4.z] + b;
    o.w = s_src[s4.w] + s_dst[d4.w] + b;
    ((float4*)out)[i] = o;
}

extern "C" void kernel_launch(void* const* d_in, const int* in_sizes, int n_in,
                              void* d_out, int out_size, void* d_ws, size_t ws_size,
                              hipStream_t stream) {
    const float* x    = (const float*)d_in[0];
    const int*   ei   = (const int*)d_in[1];
    const float* W1l  = (const float*)d_in[2];
    const float* b1l  = (const float*)d_in[3];
    const float* W1r  = (const float*)d_in[4];
    const float* W2l  = (const float*)d_in[5];
    const float* b2l  = (const float*)d_in[6];
    const float* W2r  = (const float*)d_in[7];
    const float* Wlin = (const float*)d_in[8];
    const float* blin = (const float*)d_in[9];
    float* out = (float*)d_out;

    const int* src = ei;
    const int* dst = ei + N_EDGES;

    // Workspace (~46 MB; <= R8's proven extent)
    char* w = (char*)d_ws;
    bf16*  xb    = (bf16*)w;  w += (size_t)N_NODES * 64 * 2;  // 12.8 MB
    bf16*  mean  = (bf16*)w;  w += (size_t)N_NODES * 64 * 2;  // 12.8 MB
    bf16*  h1    = (bf16*)w;  w += (size_t)N_NODES * 64 * 2;  // 12.8 MB
    float* ssrc  = (float*)w; w += (size_t)N_NODES * 4;
    float* sdst  = (float*)w; w += (size_t)N_NODES * 4;
    int*   offs  = (int*)w;   w += (size_t)(N_NODES + 4) * 4;
    int*   bhist = (int*)w;   w += 256 * 4;
    int*   bases = (int*)w;   w += 260 * 4;
    int*   gcur  = (int*)w;   w += 256 * 4;
    int*   csr   = (int*)w;   w += (size_t)N_EDGES * 4;       // 6.4 MB
    int*   pk    = (int*)mean;   // aliases mean: pk dead before agg1 writes mean

    const int conv_blocks = (N_NODES * 64 / 4) / 256;  // 6250
    const int agg_blocks  = (N_NODES + 3) / 4;         // 25000
    const int node_blocks = (N_NODES + 63) / 64;       // 1563
    const int eo_blocks   = (N_EDGES / 4 + 255) / 256; // 1563

    // ---- x -> bf16 + bucketed CSR build ----
    convert_kernel<<<conv_blocks, 256, 0, stream>>>(x, xb);
    (void)hipMemsetAsync(bhist, 0, 256 * 4, stream);
    bucket_hist<<<PART_BLOCKS, 256, 0, stream>>>(dst, bhist);
    bucket_scan<<<1, 256, 0, stream>>>(bhist, bases, gcur);
    partition_kernel<<<PART_BLOCKS, 256, 0, stream>>>(src, dst, gcur, pk);
    csr_build<<<NBUCK, 512, 0, stream>>>(bases, pk, csr, offs);

    // ---- Layer 1 ----
    aggregate_mean<<<agg_blocks, 256, 0, stream>>>(xb, offs, csr, mean);
    node_layer1_mfma<<<node_blocks, 256, 0, stream>>>(xb, mean, W1l, b1l, W1r, h1);

    // ---- Layer 2 (mean buffer reused) ----
    aggregate_mean<<<agg_blocks, 256, 0, stream>>>(h1, offs, csr, mean);
    node_layer2_mfma<<<node_blocks, 256, 0, stream>>>(h1, mean, W2l, b2l, W2r, Wlin, ssrc, sdst);

    // ---- Edge scores ----
    edge_out_kernel<<<eo_blocks, 256, 0, stream>>>(src, dst, ssrc, sdst, blin, out);
}

// Round 11
// 281.539 us; speedup vs baseline: 1.4365x; 1.1175x over previous
//
#include <hip/hip_runtime.h>
#include <hip/hip_bf16.h>

#define N_NODES 100000
#define N_EDGES 1600000
#define NBUCK 196                 // ceil(100000/512) node buckets (512 nodes each)
#define BCAP 12288                // per-bucket capacity (avg 8192, +45 sigma)
#define CHUNK 4096                // edges per partition block
#define PART_BLOCKS 391           // ceil(1600000/4096)

// Float tensors are genuine fp32 (confirmed R3-vs-R5). Internal compute bf16
// via MFMA; output fp32. ws_size = 256 MiB (R10: harness poison fill).

typedef __hip_bfloat16 bf16;
typedef short short8 __attribute__((ext_vector_type(8)));
typedef float f32x4 __attribute__((ext_vector_type(4)));
typedef unsigned int uint;

__device__ __forceinline__ short f2bs(float f) {
    bf16 h = __float2bfloat16(f);
    short s; __builtin_memcpy(&s, &h, 2); return s;
}
__device__ __forceinline__ float lo_bf(uint w) {
    uint v = w << 16; float f; __builtin_memcpy(&f, &v, 4); return f;
}
__device__ __forceinline__ float hi_bf(uint w) {
    uint v = w & 0xFFFF0000u; float f; __builtin_memcpy(&f, &v, 4); return f;
}
__device__ __forceinline__ uint pack2(float a, float b) {
    return (uint)(unsigned short)f2bs(a) | ((uint)(unsigned short)f2bs(b) << 16);
}
__device__ __forceinline__ short8 cvt8(const float* __restrict__ p) {
    float4 v0 = *(const float4*)p;
    float4 v1 = *(const float4*)(p + 4);
    short8 t;
    t[0] = f2bs(v0.x); t[1] = f2bs(v0.y); t[2] = f2bs(v0.z); t[3] = f2bs(v0.w);
    t[4] = f2bs(v1.x); t[5] = f2bs(v1.y); t[6] = f2bs(v1.z); t[7] = f2bs(v1.w);
    return t;
}
__device__ __forceinline__ short8 load8bf(const bf16* __restrict__ p, long idx) {
    return *(const short8*)((const short*)p + idx);
}

// ---- x -> bf16 conversion + gcur init ---------------------------------
__global__ __launch_bounds__(256) void convert_kernel(
    const float* __restrict__ in, bf16* __restrict__ out, int* __restrict__ gcur)
{
    int i = blockIdx.x * 256 + threadIdx.x;      // 1.6M threads x 4 elems
    float4 v = ((const float4*)in)[i];
    uint2 o;
    o.x = pack2(v.x, v.y);
    o.y = pack2(v.z, v.w);
    ((uint2*)out)[i] = o;
    if (blockIdx.x == 0) gcur[threadIdx.x] = threadIdx.x * BCAP;  // bucket cursors
}

// ---- Bucketed CSR build (fixed-stride regions, no global hist/scan) ----
// Bucket b = dst >> 9 (512 nodes). pk/csr regions are b*BCAP..(b+1)*BCAP.
// Payload packs src (17b) | local dst (9b) << 17.

__global__ __launch_bounds__(256) void partition_kernel(
    const int* __restrict__ src, const int* __restrict__ dst,
    int* __restrict__ gcur, int* __restrict__ pk)
{
    __shared__ int h[256], scn[256], cur[256], gb[256];
    __shared__ int pl[CHUNK];
    __shared__ unsigned char bb[CHUNK];
    int t = threadIdx.x;
    h[t] = 0;
    __syncthreads();
    int e0 = blockIdx.x * CHUNK;
    // pass 1: local histogram
    for (int i = t; i < CHUNK; i += 256) {
        int e = e0 + i;
        if (e < N_EDGES) atomicAdd(&h[dst[e] >> 9], 1);
    }
    __syncthreads();
    scn[t] = h[t];
    __syncthreads();
#pragma unroll
    for (int off = 1; off < 256; off <<= 1) {
        int add = (t >= off) ? scn[t - off] : 0;
        __syncthreads();
        scn[t] += add;
        __syncthreads();
    }
    cur[t] = scn[t] - h[t];
    __syncthreads();
    int cnt_local = scn[255];
    // pass 2: LDS bucket-sort
    for (int i = t; i < CHUNK; i += 256) {
        int e = e0 + i;
        if (e < N_EDGES) {
            int d = dst[e];
            int b = d >> 9;
            int p = atomicAdd(&cur[b], 1);
            pl[p] = src[e] | ((d & 511) << 17);
            bb[p] = (unsigned char)b;
        }
    }
    __syncthreads();
    // reserve a contiguous run per bucket
    if (h[t] > 0) gb[t] = atomicAdd(&gcur[t], h[t]);
    __syncthreads();
    // coalesced flush (guard fixed-capacity overflow)
    for (int i = t; i < cnt_local; i += 256) {
        int b = bb[i];
        int pos = gb[b] + (i - (scn[b] - h[b]));
        if (pos < (b + 1) * BCAP) pk[pos] = pl[i];
    }
}

// Per bucket: LDS deg-hist -> scan -> scatter -> sequential csr + ranges.
__global__ __launch_bounds__(512) void csr_build(
    const int* __restrict__ gcur, const int* __restrict__ pk,
    int* __restrict__ csr, int2* __restrict__ node_range)
{
    __shared__ int deg[512], scn[512], cur[512];
    __shared__ int csr_l[BCAP];
    int t = threadIdx.x;
    int b = blockIdx.x;
    int base = b * BCAP;
    int cnt = gcur[b] - base;
    if (cnt > BCAP) cnt = BCAP;
    deg[t] = 0;
    __syncthreads();
    for (int i = t; i < cnt; i += 512)
        atomicAdd(&deg[pk[base + i] >> 17], 1);
    __syncthreads();
    scn[t] = deg[t];
    __syncthreads();
#pragma unroll
    for (int off = 1; off < 512; off <<= 1) {
        int add = (t >= off) ? scn[t - off] : 0;
        __syncthreads();
        scn[t] += add;
        __syncthreads();
    }
    int excl = scn[t] - deg[t];
    cur[t] = excl;
    int n = (b << 9) + t;
    if (n < N_NODES) node_range[n] = make_int2(base + excl, base + excl + deg[t]);
    __syncthreads();
    for (int i = t; i < cnt; i += 512) {
        int v = pk[base + i];
        int p = atomicAdd(&cur[v >> 17], 1);
        csr_l[p] = v & 0x1FFFF;
    }
    __syncthreads();
    for (int i = t; i < cnt; i += 512)
        csr[base + i] = csr_l[i];
}

// ---- Mean aggregation (gather, bf16 source) ---------------------------
// One wave per node. Lane j: row-slot ri=j>>3, 16B chunk ci=j&7.
// Unroll-2: 16 rows in flight per wave (R10: 8-in-flight was latency-bound).
__global__ __launch_bounds__(256) void aggregate_mean(
    const bf16* __restrict__ feat, const int2* __restrict__ node_range,
    const int* __restrict__ csr, bf16* __restrict__ mean)
{
    int wave = threadIdx.x >> 6, lane = threadIdx.x & 63;
    int ri = lane >> 3, ci = lane & 7;
    int n = blockIdx.x * 4 + wave;
    if (n >= N_NODES) return;
    int2 rg = node_range[n];
    int beg = rg.x, end = rg.y;
    const uint* fw = (const uint*)feat;
    float acc[8] = {0.f, 0.f, 0.f, 0.f, 0.f, 0.f, 0.f, 0.f};
    int i = beg + ri;
    for (; i + 8 < end; i += 16) {          // two row-slots in flight per lane
        int s0 = csr[i], s1 = csr[i + 8];
        uint4 w0 = *(const uint4*)(fw + (long)s0 * 32 + ci * 4);
        uint4 w1 = *(const uint4*)(fw + (long)s1 * 32 + ci * 4);
        acc[0] += lo_bf(w0.x) + lo_bf(w1.x); acc[1] += hi_bf(w0.x) + hi_bf(w1.x);
        acc[2] += lo_bf(w0.y) + lo_bf(w1.y); acc[3] += hi_bf(w0.y) + hi_bf(w1.y);
        acc[4] += lo_bf(w0.z) + lo_bf(w1.z); acc[5] += hi_bf(w0.z) + hi_bf(w1.z);
        acc[6] += lo_bf(w0.w) + lo_bf(w1.w); acc[7] += hi_bf(w0.w) + hi_bf(w1.w);
    }
    if (i < end) {
        int s = csr[i];
        uint4 w = *(const uint4*)(fw + (long)s * 32 + ci * 4);
        acc[0] += lo_bf(w.x); acc[1] += hi_bf(w.x);
        acc[2] += lo_bf(w.y); acc[3] += hi_bf(w.y);
        acc[4] += lo_bf(w.z); acc[5] += hi_bf(w.z);
        acc[6] += lo_bf(w.w); acc[7] += hi_bf(w.w);
    }
#pragma unroll
    for (int m = 8; m < 64; m <<= 1) {
#pragma unroll
        for (int k = 0; k < 8; k++) acc[k] += __shfl_xor(acc[k], m);
    }
    if (ri == 0) {
        int d = end - beg;
        float inv = d > 0 ? 1.0f / (float)d : 0.0f;
        short8 st;
#pragma unroll
        for (int k = 0; k < 8; k++) st[k] = f2bs(acc[k] * inv);
        *(short8*)((short*)mean + (long)n * 64 + ci * 8) = st;
    }
}

// ---- MFMA node layers (verified R6) -----------------------------------
__device__ __forceinline__ void load_afrags(
    short8* a, const bf16* __restrict__ mean,
    const bf16* __restrict__ self, int na, int quad)
{
#pragma unroll
    for (int c = 0; c < 2; c++)
        a[c] = load8bf(mean, (long)na * 64 + c * 32 + quad * 8);
#pragma unroll
    for (int c = 0; c < 2; c++)
        a[2 + c] = load8bf(self, (long)na * 64 + c * 32 + quad * 8);
}

__device__ __forceinline__ short8 load_bfrag(
    const float* __restrict__ Wl, const float* __restrict__ Wr,
    int f, int c, int quad)
{
    if (c < 2) return cvt8(Wl + (long)f * 64 + c * 32 + quad * 8);
    return cvt8(Wr + (long)f * 64 + (c - 2) * 32 + quad * 8);
}

__global__ __launch_bounds__(256) void node_layer1_mfma(
    const bf16* __restrict__ xb, const bf16* __restrict__ mean,
    const float* __restrict__ Wl, const float* __restrict__ bl,
    const float* __restrict__ Wr, bf16* __restrict__ h_out)
{
    int tid = threadIdx.x;
    int wave = tid >> 6, lane = tid & 63;
    int quad = lane >> 4, n16 = lane & 15;
    int nb = (blockIdx.x * 4 + wave) * 16;

    int node_a = nb + n16;
    int na = node_a < N_NODES ? node_a : N_NODES - 1;
    short8 a[4];
    load_afrags(a, mean, xb, na, quad);

#pragma unroll
    for (int t = 0; t < 4; t++) {
        int f = 16 * t + n16;
        f32x4 acc = {0.f, 0.f, 0.f, 0.f};
#pragma unroll
        for (int c = 0; c < 4; c++) {
            short8 b = load_bfrag(Wl, Wr, f, c, quad);
            acc = __builtin_amdgcn_mfma_f32_16x16x32_bf16(a[c], b, acc, 0, 0, 0);
        }
        float bias = bl[f];
#pragma unroll
        for (int r = 0; r < 4; r++) {
            int node = nb + quad * 4 + r;
            if (node < N_NODES)
                h_out[(long)node * 64 + f] = __float2bfloat16(fmaxf(acc[r] + bias, 0.0f));
        }
    }
}

__global__ __launch_bounds__(256) void node_layer2_mfma(
    const bf16* __restrict__ h1, const bf16* __restrict__ mean,
    const float* __restrict__ Wl, const float* __restrict__ bl,
    const float* __restrict__ Wr, const float* __restrict__ Wlin,
    float* __restrict__ s_src, float* __restrict__ s_dst)
{
    int tid = threadIdx.x;
    int wave = tid >> 6, lane = tid & 63;
    int quad = lane >> 4, n16 = lane & 15;
    int nb = (blockIdx.x * 4 + wave) * 16;

    int node_a = nb + n16;
    int na = node_a < N_NODES ? node_a : N_NODES - 1;
    short8 a[4];
    load_afrags(a, mean, h1, na, quad);

    float sa[4] = {0.f, 0.f, 0.f, 0.f};
    float sb[4] = {0.f, 0.f, 0.f, 0.f};
#pragma unroll
    for (int t = 0; t < 4; t++) {
        int f = 16 * t + n16;
        f32x4 acc = {0.f, 0.f, 0.f, 0.f};
#pragma unroll
        for (int c = 0; c < 4; c++) {
            short8 b = load_bfrag(Wl, Wr, f, c, quad);
            acc = __builtin_amdgcn_mfma_f32_16x16x32_bf16(a[c], b, acc, 0, 0, 0);
        }
        float bias = bl[f];
        float wa = Wlin[f];
        float wb = Wlin[64 + f];
#pragma unroll
        for (int r = 0; r < 4; r++) {
            float h = fmaxf(acc[r] + bias, 0.0f);
            sa[r] += h * wa;
            sb[r] += h * wb;
        }
    }
#pragma unroll
    for (int m = 1; m < 16; m <<= 1) {
#pragma unroll
        for (int r = 0; r < 4; r++) {
            sa[r] += __shfl_xor(sa[r], m);
            sb[r] += __shfl_xor(sb[r], m);
        }
    }
    if (n16 == 0) {
#pragma unroll
        for (int r = 0; r < 4; r++) {
            int node = nb + quad * 4 + r;
            if (node < N_NODES) { s_src[node] = sa[r]; s_dst[node] = sb[r]; }
        }
    }
}

__global__ __launch_bounds__(256) void edge_out_kernel(
    const int* __restrict__ src, const int* __restrict__ dst,
    const float* __restrict__ s_src, const float* __restrict__ s_dst,
    const float* __restrict__ blin, float* __restrict__ out)
{
    int i = blockIdx.x * 256 + threadIdx.x;
    if (i >= N_EDGES / 4) return;
    int4 s4 = ((const int4*)src)[i];
    int4 d4 = ((const int4*)dst)[i];
    float b = blin[0];
    float4 o;
    o.x = s_src[s4.x] + s_dst[d4.x] + b;
    o.y = s_src[s4.y] + s_dst[d4.y] + b;
    o.z = s_src[s4.z] + s_dst[d4.z] + b;
    o.w = s_src[s4.w] + s_dst[d4.w] + b;
    ((float4*)out)[i] = o;
}

extern "C" void kernel_launch(void* const* d_in, const int* in_sizes, int n_in,
                              void* d_out, int out_size, void* d_ws, size_t ws_size,
                              hipStream_t stream) {
    const float* x    = (const float*)d_in[0];
    const int*   ei   = (const int*)d_in[1];
    const float* W1l  = (const float*)d_in[2];
    const float* b1l  = (const float*)d_in[3];
    const float* W1r  = (const float*)d_in[4];
    const float* W2l  = (const float*)d_in[5];
    const float* b2l  = (const float*)d_in[6];
    const float* W2r  = (const float*)d_in[7];
    const float* Wlin = (const float*)d_in[8];
    const float* blin = (const float*)d_in[9];
    float* out = (float*)d_out;

    const int* src = ei;
    const int* dst = ei + N_EDGES;

    // Workspace (~60 MB of the 256 MiB ws; every byte read is written first)
    char* w = (char*)d_ws;
    bf16*  xb    = (bf16*)w;  w += (size_t)N_NODES * 64 * 2;   // 12.8 MB
    bf16*  mean  = (bf16*)w;  w += (size_t)N_NODES * 64 * 2;   // 12.8 MB
    bf16*  h1    = (bf16*)w;  w += (size_t)N_NODES * 64 * 2;   // 12.8 MB
    float* ssrc  = (float*)w; w += (size_t)N_NODES * 4;
    float* sdst  = (float*)w; w += (size_t)N_NODES * 4;
    int2*  nrng  = (int2*)w;  w += (size_t)N_NODES * 8;        // 0.8 MB
    int*   gcur  = (int*)w;   w += 256 * 4;
    int*   pk    = (int*)w;   w += (size_t)NBUCK * BCAP * 4;   // 9.6 MB
    int*   csr   = (int*)w;   w += (size_t)NBUCK * BCAP * 4;   // 9.6 MB

    const int conv_blocks = (N_NODES * 64 / 4) / 256;  // 6250
    const int agg_blocks  = (N_NODES + 3) / 4;         // 25000
    const int node_blocks = (N_NODES + 63) / 64;       // 1563
    const int eo_blocks   = (N_EDGES / 4 + 255) / 256; // 1563

    // ---- x -> bf16 (+ gcur init) + bucketed CSR build ----
    convert_kernel<<<conv_blocks, 256, 0, stream>>>(x, xb, gcur);
    partition_kernel<<<PART_BLOCKS, 256, 0, stream>>>(src, dst, gcur, pk);
    csr_build<<<NBUCK, 512, 0, stream>>>(gcur, pk, csr, nrng);

    // ---- Layer 1 ----
    aggregate_mean<<<agg_blocks, 256, 0, stream>>>(xb, nrng, csr, mean);
    node_layer1_mfma<<<node_blocks, 256, 0, stream>>>(xb, mean, W1l, b1l, W1r, h1);

    // ---- Layer 2 (mean buffer reused) ----
    aggregate_mean<<<agg_blocks, 256, 0, stream>>>(h1, nrng, csr, mean);
    node_layer2_mfma<<<node_blocks, 256, 0, stream>>>(h1, mean, W2l, b2l, W2r, Wlin, ssrc, sdst);

    // ---- Edge scores ----
    edge_out_kernel<<<eo_blocks, 256, 0, stream>>>(src, dst, ssrc, sdst, blin, out);
}

// Round 12
// 257.696 us; speedup vs baseline: 1.5694x; 1.0925x over previous
//
#include <hip/hip_runtime.h>
#include <hip/hip_bf16.h>

#define N_NODES 100000
#define N_EDGES 1600000
#define NBUCK 196                 // ceil(100000/512) node buckets (512 nodes each)
#define BCAP 12288                // per-bucket capacity (avg 8192, +45 sigma)
#define CHUNK 4096                // edges per partition block
#define PART_BLOCKS 391           // ceil(1600000/4096)

// Float tensors are genuine fp32 (confirmed R3-vs-R5). Internal compute bf16
// via MFMA; output fp32. ws_size = 256 MiB (R10: harness poison fill).

typedef __hip_bfloat16 bf16;
typedef short short8 __attribute__((ext_vector_type(8)));
typedef float f32x4 __attribute__((ext_vector_type(4)));
typedef unsigned int uint;

__device__ __forceinline__ short f2bs(float f) {
    bf16 h = __float2bfloat16(f);
    short s; __builtin_memcpy(&s, &h, 2); return s;
}
__device__ __forceinline__ float lo_bf(uint w) {
    uint v = w << 16; float f; __builtin_memcpy(&f, &v, 4); return f;
}
__device__ __forceinline__ float hi_bf(uint w) {
    uint v = w & 0xFFFF0000u; float f; __builtin_memcpy(&f, &v, 4); return f;
}
__device__ __forceinline__ uint pack2(float a, float b) {
    return (uint)(unsigned short)f2bs(a) | ((uint)(unsigned short)f2bs(b) << 16);
}
__device__ __forceinline__ short8 load8bf(const bf16* __restrict__ p, long idx) {
    return *(const short8*)((const short*)p + idx);
}

// ---- x -> bf16 conversion + weight conversion + gcur init -------------
// Blocks 0..6249: convert x (4 elems/thread). Block 6250: convert the four
// 64x64 weight matrices to bf16 (wb = [W1l|W1r|W2l|W2r]).
__global__ __launch_bounds__(256) void convert_kernel(
    const float* __restrict__ in, bf16* __restrict__ out, int* __restrict__ gcur,
    const float* __restrict__ W1l, const float* __restrict__ W1r,
    const float* __restrict__ W2l, const float* __restrict__ W2r,
    bf16* __restrict__ wb)
{
    if (blockIdx.x < 6250) {
        int i = blockIdx.x * 256 + threadIdx.x;
        float4 v = ((const float4*)in)[i];
        uint2 o;
        o.x = pack2(v.x, v.y);
        o.y = pack2(v.z, v.w);
        ((uint2*)out)[i] = o;
        if (blockIdx.x == 0) gcur[threadIdx.x] = threadIdx.x * BCAP;
    } else {
        for (int k = threadIdx.x; k < 16384; k += 256) {
            float v;
            if (k < 4096)       v = W1l[k];
            else if (k < 8192)  v = W1r[k - 4096];
            else if (k < 12288) v = W2l[k - 8192];
            else                v = W2r[k - 12288];
            wb[k] = __float2bfloat16(v);
        }
    }
}

// ---- Bucketed CSR build (fixed-stride regions) -------------------------
// Bucket b = dst >> 9 (512 nodes). pk/csr regions are b*BCAP..(b+1)*BCAP.
// Payload packs src (17b) | local dst (9b) << 17.

__global__ __launch_bounds__(256) void partition_kernel(
    const int* __restrict__ src, const int* __restrict__ dst,
    int* __restrict__ gcur, int* __restrict__ pk)
{
    __shared__ int h[256], scn[256], cur[256], gb[256];
    __shared__ int pl[CHUNK];
    __shared__ unsigned char bb[CHUNK];
    int t = threadIdx.x;
    h[t] = 0;
    __syncthreads();
    int e0 = blockIdx.x * CHUNK;
    for (int i = t; i < CHUNK; i += 256) {
        int e = e0 + i;
        if (e < N_EDGES) atomicAdd(&h[dst[e] >> 9], 1);
    }
    __syncthreads();
    scn[t] = h[t];
    __syncthreads();
#pragma unroll
    for (int off = 1; off < 256; off <<= 1) {
        int add = (t >= off) ? scn[t - off] : 0;
        __syncthreads();
        scn[t] += add;
        __syncthreads();
    }
    cur[t] = scn[t] - h[t];
    __syncthreads();
    int cnt_local = scn[255];
    for (int i = t; i < CHUNK; i += 256) {
        int e = e0 + i;
        if (e < N_EDGES) {
            int d = dst[e];
            int b = d >> 9;
            int p = atomicAdd(&cur[b], 1);
            pl[p] = src[e] | ((d & 511) << 17);
            bb[p] = (unsigned char)b;
        }
    }
    __syncthreads();
    if (h[t] > 0) gb[t] = atomicAdd(&gcur[t], h[t]);
    __syncthreads();
    for (int i = t; i < cnt_local; i += 256) {
        int b = bb[i];
        int pos = gb[b] + (i - (scn[b] - h[b]));
        if (pos < (b + 1) * BCAP) pk[pos] = pl[i];
    }
}

// Per bucket: LDS deg-hist -> scan -> scatter -> sequential csr + ranges.
__global__ __launch_bounds__(512) void csr_build(
    const int* __restrict__ gcur, const int* __restrict__ pk,
    int* __restrict__ csr, int2* __restrict__ node_range)
{
    __shared__ int deg[512], scn[512], cur[512];
    __shared__ int csr_l[BCAP];
    int t = threadIdx.x;
    int b = blockIdx.x;
    int base = b * BCAP;
    int cnt = gcur[b] - base;
    if (cnt > BCAP) cnt = BCAP;
    deg[t] = 0;
    __syncthreads();
    for (int i = t; i < cnt; i += 512)
        atomicAdd(&deg[pk[base + i] >> 17], 1);
    __syncthreads();
    scn[t] = deg[t];
    __syncthreads();
#pragma unroll
    for (int off = 1; off < 512; off <<= 1) {
        int add = (t >= off) ? scn[t - off] : 0;
        __syncthreads();
        scn[t] += add;
        __syncthreads();
    }
    int excl = scn[t] - deg[t];
    cur[t] = excl;
    int n = (b << 9) + t;
    if (n < N_NODES) node_range[n] = make_int2(base + excl, base + excl + deg[t]);
    __syncthreads();
    for (int i = t; i < cnt; i += 512) {
        int v = pk[base + i];
        int p = atomicAdd(&cur[v >> 17], 1);
        csr_l[p] = v & 0x1FFFF;
    }
    __syncthreads();
    for (int i = t; i < cnt; i += 512)
        csr[base + i] = csr_l[i];
}

// ---- Mean aggregation (gather, bf16 source) ---------------------------
// Wave handles 8 nodes: group g=lane>>3 (node), chunk ci=lane&7 (16B of row).
// Each lane walks its node's csr with unroll-4 -> 32 row-loads in flight per
// wave, ZERO cross-lane reduction (lane's accumulator is final), direct
// coalesced uint4 store. (R10/R11 shfl-reduce versions were latency-bound.)
__global__ __launch_bounds__(256) void aggregate_mean(
    const bf16* __restrict__ feat, const int2* __restrict__ node_range,
    const int* __restrict__ csr, bf16* __restrict__ mean)
{
    int wave = threadIdx.x >> 6, lane = threadIdx.x & 63;
    int g = lane >> 3, ci = lane & 7;
    int n = (blockIdx.x * 4 + wave) * 8 + g;       // 3125*32 = 100000 exact
    int2 rg = node_range[n];
    int beg = rg.x, end = rg.y;
    const uint* fw = (const uint*)feat;
    float a0 = 0.f, a1 = 0.f, a2 = 0.f, a3 = 0.f;
    float a4 = 0.f, a5 = 0.f, a6 = 0.f, a7 = 0.f;
    int i = beg;
    for (; i + 3 < end; i += 4) {                  // 4 rows in flight per lane
        int s0 = csr[i], s1 = csr[i + 1], s2 = csr[i + 2], s3 = csr[i + 3];
        uint4 w0 = *(const uint4*)(fw + (long)s0 * 32 + ci * 4);
        uint4 w1 = *(const uint4*)(fw + (long)s1 * 32 + ci * 4);
        uint4 w2 = *(const uint4*)(fw + (long)s2 * 32 + ci * 4);
        uint4 w3 = *(const uint4*)(fw + (long)s3 * 32 + ci * 4);
        a0 += lo_bf(w0.x) + lo_bf(w1.x) + lo_bf(w2.x) + lo_bf(w3.x);
        a1 += hi_bf(w0.x) + hi_bf(w1.x) + hi_bf(w2.x) + hi_bf(w3.x);
        a2 += lo_bf(w0.y) + lo_bf(w1.y) + lo_bf(w2.y) + lo_bf(w3.y);
        a3 += hi_bf(w0.y) + hi_bf(w1.y) + hi_bf(w2.y) + hi_bf(w3.y);
        a4 += lo_bf(w0.z) + lo_bf(w1.z) + lo_bf(w2.z) + lo_bf(w3.z);
        a5 += hi_bf(w0.z) + hi_bf(w1.z) + hi_bf(w2.z) + hi_bf(w3.z);
        a6 += lo_bf(w0.w) + lo_bf(w1.w) + lo_bf(w2.w) + lo_bf(w3.w);
        a7 += hi_bf(w0.w) + hi_bf(w1.w) + hi_bf(w2.w) + hi_bf(w3.w);
    }
    for (; i < end; i++) {
        int s = csr[i];
        uint4 w = *(const uint4*)(fw + (long)s * 32 + ci * 4);
        a0 += lo_bf(w.x); a1 += hi_bf(w.x);
        a2 += lo_bf(w.y); a3 += hi_bf(w.y);
        a4 += lo_bf(w.z); a5 += hi_bf(w.z);
        a6 += lo_bf(w.w); a7 += hi_bf(w.w);
    }
    int d = end - beg;
    float inv = d > 0 ? 1.0f / (float)d : 0.0f;
    uint4 q;
    q.x = pack2(a0 * inv, a1 * inv);
    q.y = pack2(a2 * inv, a3 * inv);
    q.z = pack2(a4 * inv, a5 * inv);
    q.w = pack2(a6 * inv, a7 * inv);
    *(uint4*)((uint*)mean + (long)n * 32 + ci * 4) = q;
}

// ---- MFMA node layers (verified R6; bf16 weights as of R12) ------------
__device__ __forceinline__ void load_afrags(
    short8* a, const bf16* __restrict__ mean,
    const bf16* __restrict__ self, int na, int quad)
{
#pragma unroll
    for (int c = 0; c < 2; c++)
        a[c] = load8bf(mean, (long)na * 64 + c * 32 + quad * 8);
#pragma unroll
    for (int c = 0; c < 2; c++)
        a[2 + c] = load8bf(self, (long)na * 64 + c * 32 + quad * 8);
}

// wlb = [Wl | Wr] bf16, each 4096
__device__ __forceinline__ short8 load_bfrag(
    const bf16* __restrict__ wlb, int f, int c, int quad)
{
    if (c < 2) return load8bf(wlb, (long)f * 64 + c * 32 + quad * 8);
    return load8bf(wlb, 4096 + (long)f * 64 + (c - 2) * 32 + quad * 8);
}

__global__ __launch_bounds__(256) void node_layer1_mfma(
    const bf16* __restrict__ xb, const bf16* __restrict__ mean,
    const bf16* __restrict__ wlb, const float* __restrict__ bl,
    bf16* __restrict__ h_out)
{
    int tid = threadIdx.x;
    int wave = tid >> 6, lane = tid & 63;
    int quad = lane >> 4, n16 = lane & 15;
    int nb = (blockIdx.x * 4 + wave) * 16;

    int node_a = nb + n16;
    int na = node_a < N_NODES ? node_a : N_NODES - 1;
    short8 a[4];
    load_afrags(a, mean, xb, na, quad);

#pragma unroll
    for (int t = 0; t < 4; t++) {
        int f = 16 * t + n16;
        f32x4 acc = {0.f, 0.f, 0.f, 0.f};
#pragma unroll
        for (int c = 0; c < 4; c++) {
            short8 b = load_bfrag(wlb, f, c, quad);
            acc = __builtin_amdgcn_mfma_f32_16x16x32_bf16(a[c], b, acc, 0, 0, 0);
        }
        float bias = bl[f];
#pragma unroll
        for (int r = 0; r < 4; r++) {
            int node = nb + quad * 4 + r;
            if (node < N_NODES)
                h_out[(long)node * 64 + f] = __float2bfloat16(fmaxf(acc[r] + bias, 0.0f));
        }
    }
}

__global__ __launch_bounds__(256) void node_layer2_mfma(
    const bf16* __restrict__ h1, const bf16* __restrict__ mean,
    const bf16* __restrict__ wlb, const float* __restrict__ bl,
    const float* __restrict__ Wlin,
    float* __restrict__ s_src, float* __restrict__ s_dst)
{
    int tid = threadIdx.x;
    int wave = tid >> 6, lane = tid & 63;
    int quad = lane >> 4, n16 = lane & 15;
    int nb = (blockIdx.x * 4 + wave) * 16;

    int node_a = nb + n16;
    int na = node_a < N_NODES ? node_a : N_NODES - 1;
    short8 a[4];
    load_afrags(a, mean, h1, na, quad);

    float sa[4] = {0.f, 0.f, 0.f, 0.f};
    float sb[4] = {0.f, 0.f, 0.f, 0.f};
#pragma unroll
    for (int t = 0; t < 4; t++) {
        int f = 16 * t + n16;
        f32x4 acc = {0.f, 0.f, 0.f, 0.f};
#pragma unroll
        for (int c = 0; c < 4; c++) {
            short8 b = load_bfrag(wlb, f, c, quad);
            acc = __builtin_amdgcn_mfma_f32_16x16x32_bf16(a[c], b, acc, 0, 0, 0);
        }
        float bias = bl[f];
        float wa = Wlin[f];
        float wb = Wlin[64 + f];
#pragma unroll
        for (int r = 0; r < 4; r++) {
            float h = fmaxf(acc[r] + bias, 0.0f);
            sa[r] += h * wa;
            sb[r] += h * wb;
        }
    }
#pragma unroll
    for (int m = 1; m < 16; m <<= 1) {
#pragma unroll
        for (int r = 0; r < 4; r++) {
            sa[r] += __shfl_xor(sa[r], m);
            sb[r] += __shfl_xor(sb[r], m);
        }
    }
    if (n16 == 0) {
#pragma unroll
        for (int r = 0; r < 4; r++) {
            int node = nb + quad * 4 + r;
            if (node < N_NODES) { s_src[node] = sa[r]; s_dst[node] = sb[r]; }
        }
    }
}

__global__ __launch_bounds__(256) void edge_out_kernel(
    const int* __restrict__ src, const int* __restrict__ dst,
    const float* __restrict__ s_src, const float* __restrict__ s_dst,
    const float* __restrict__ blin, float* __restrict__ out)
{
    int i = blockIdx.x * 256 + threadIdx.x;
    if (i >= N_EDGES / 4) return;
    int4 s4 = ((const int4*)src)[i];
    int4 d4 = ((const int4*)dst)[i];
    float b = blin[0];
    float4 o;
    o.x = s_src[s4.x] + s_dst[d4.x] + b;
    o.y = s_src[s4.y] + s_dst[d4.y] + b;
    o.z = s_src[s4.z] + s_dst[d4.z] + b;
    o.w = s_src[s4.w] + s_dst[d4.w] + b;
    ((float4*)out)[i] = o;
}

extern "C" void kernel_launch(void* const* d_in, const int* in_sizes, int n_in,
                              void* d_out, int out_size, void* d_ws, size_t ws_size,
                              hipStream_t stream) {
    const float* x    = (const float*)d_in[0];
    const int*   ei   = (const int*)d_in[1];
    const float* W1l  = (const float*)d_in[2];
    const float* b1l  = (const float*)d_in[3];
    const float* W1r  = (const float*)d_in[4];
    const float* W2l  = (const float*)d_in[5];
    const float* b2l  = (const float*)d_in[6];
    const float* W2r  = (const float*)d_in[7];
    const float* Wlin = (const float*)d_in[8];
    const float* blin = (const float*)d_in[9];
    float* out = (float*)d_out;

    const int* src = ei;
    const int* dst = ei + N_EDGES;

    // Workspace (~60 MB of 256 MiB; every byte read is written first)
    char* w = (char*)d_ws;
    bf16*  xb    = (bf16*)w;  w += (size_t)N_NODES * 64 * 2;   // 12.8 MB
    bf16*  mean  = (bf16*)w;  w += (size_t)N_NODES * 64 * 2;   // 12.8 MB
    bf16*  h1    = (bf16*)w;  w += (size_t)N_NODES * 64 * 2;   // 12.8 MB
    float* ssrc  = (float*)w; w += (size_t)N_NODES * 4;
    float* sdst  = (float*)w; w += (size_t)N_NODES * 4;
    int2*  nrng  = (int2*)w;  w += (size_t)N_NODES * 8;        // 0.8 MB
    int*   gcur  = (int*)w;   w += 256 * 4;
    bf16*  wb    = (bf16*)w;  w += 16384 * 2;                  // 32 KB bf16 weights
    int*   pk    = (int*)w;   w += (size_t)NBUCK * BCAP * 4;   // 9.6 MB
    int*   csr   = (int*)w;   w += (size_t)NBUCK * BCAP * 4;   // 9.6 MB

    const int conv_blocks = 6251;                      // 6250 x-convert + 1 weights
    const int agg_blocks  = N_NODES / 32;              // 3125 (8 nodes/wave)
    const int node_blocks = (N_NODES + 63) / 64;       // 1563
    const int eo_blocks   = (N_EDGES / 4 + 255) / 256; // 1563

    // ---- x/weights -> bf16 (+ gcur init) + bucketed CSR build ----
    convert_kernel<<<conv_blocks, 256, 0, stream>>>(x, xb, gcur, W1l, W1r, W2l, W2r, wb);
    partition_kernel<<<PART_BLOCKS, 256, 0, stream>>>(src, dst, gcur, pk);
    csr_build<<<NBUCK, 512, 0, stream>>>(gcur, pk, csr, nrng);

    // ---- Layer 1 ----
    aggregate_mean<<<agg_blocks, 256, 0, stream>>>(xb, nrng, csr, mean);
    node_layer1_mfma<<<node_blocks, 256, 0, stream>>>(xb, mean, wb, b1l, h1);

    // ---- Layer 2 (mean buffer reused) ----
    aggregate_mean<<<agg_blocks, 256, 0, stream>>>(h1, nrng, csr, mean);
    node_layer2_mfma<<<node_blocks, 256, 0, stream>>>(h1, mean, wb + 8192, b2l, Wlin, ssrc, sdst);

    // ---- Edge scores ----
    edge_out_kernel<<<eo_blocks, 256, 0, stream>>>(src, dst, ssrc, sdst, blin, out);
}

// Round 13
// 238.245 us; speedup vs baseline: 1.6975x; 1.0816x over previous
//
#include <hip/hip_runtime.h>
#include <hip/hip_bf16.h>

#define N_NODES 100000
#define N_EDGES 1600000
#define NBUCK 196                 // ceil(100000/512) node buckets (512 nodes each)
#define BCAP 12288                // per-bucket capacity (avg 8192, +45 sigma)
#define CHUNK 4096                // edges per partition block
#define PART_BLOCKS 391           // ceil(1600000/4096)
#define MSTRIDE 36                // LDS mean row stride in words (144B): 2-way alias on MFMA reads

// Float tensors are genuine fp32 (confirmed R3-vs-R5). Internal compute bf16
// via MFMA; output fp32. ws_size = 256 MiB (R10: harness poison fill).

typedef __hip_bfloat16 bf16;
typedef short short8 __attribute__((ext_vector_type(8)));
typedef float f32x4 __attribute__((ext_vector_type(4)));
typedef unsigned int uint;

__device__ __forceinline__ short f2bs(float f) {
    bf16 h = __float2bfloat16(f);
    short s; __builtin_memcpy(&s, &h, 2); return s;
}
__device__ __forceinline__ float lo_bf(uint w) {
    uint v = w << 16; float f; __builtin_memcpy(&f, &v, 4); return f;
}
__device__ __forceinline__ float hi_bf(uint w) {
    uint v = w & 0xFFFF0000u; float f; __builtin_memcpy(&f, &v, 4); return f;
}
__device__ __forceinline__ uint pack2(float a, float b) {
    return (uint)(unsigned short)f2bs(a) | ((uint)(unsigned short)f2bs(b) << 16);
}
__device__ __forceinline__ short8 load8bf(const bf16* __restrict__ p, long idx) {
    return *(const short8*)((const short*)p + idx);
}

// ---- x -> bf16 conversion + weight conversion + gcur init -------------
__global__ __launch_bounds__(256) void convert_kernel(
    const float* __restrict__ in, bf16* __restrict__ out, int* __restrict__ gcur,
    const float* __restrict__ W1l, const float* __restrict__ W1r,
    const float* __restrict__ W2l, const float* __restrict__ W2r,
    bf16* __restrict__ wb)
{
    if (blockIdx.x < 6250) {
        int i = blockIdx.x * 256 + threadIdx.x;
        float4 v = ((const float4*)in)[i];
        uint2 o;
        o.x = pack2(v.x, v.y);
        o.y = pack2(v.z, v.w);
        ((uint2*)out)[i] = o;
        if (blockIdx.x == 0) gcur[threadIdx.x] = threadIdx.x * BCAP;
    } else {
        for (int k = threadIdx.x; k < 16384; k += 256) {
            float v;
            if (k < 4096)       v = W1l[k];
            else if (k < 8192)  v = W1r[k - 4096];
            else if (k < 12288) v = W2l[k - 8192];
            else                v = W2r[k - 12288];
            wb[k] = __float2bfloat16(v);
        }
    }
}

// ---- Bucketed CSR build (fixed-stride regions) -------------------------
// Bucket b = dst >> 9 (512 nodes). pk/csr regions are b*BCAP..(b+1)*BCAP.
// Payload packs src (17b) | local dst (9b) << 17.

__global__ __launch_bounds__(256) void partition_kernel(
    const int* __restrict__ src, const int* __restrict__ dst,
    int* __restrict__ gcur, int* __restrict__ pk)
{
    __shared__ int h[256], scn[256], cur[256], gb[256];
    __shared__ int pl[CHUNK];
    __shared__ unsigned char bb[CHUNK];
    int t = threadIdx.x;
    h[t] = 0;
    __syncthreads();
    int e0 = blockIdx.x * CHUNK;
    for (int i = t; i < CHUNK; i += 256) {
        int e = e0 + i;
        if (e < N_EDGES) atomicAdd(&h[dst[e] >> 9], 1);
    }
    __syncthreads();
    // single-wave shfl scan (inclusive) of the 256 counts: 4 elems/lane
    if (t < 64) {
        int v0 = h[t * 4], v1 = h[t * 4 + 1], v2 = h[t * 4 + 2], v3 = h[t * 4 + 3];
        int i0 = v0, i1 = i0 + v1, i2 = i1 + v2, i3 = i2 + v3;
        int run = i3;
#pragma unroll
        for (int off = 1; off < 64; off <<= 1) {
            int u = __shfl_up(run, off);
            if (t >= off) run += u;
        }
        int excl = run - i3;
        scn[t * 4]     = excl + i0;
        scn[t * 4 + 1] = excl + i1;
        scn[t * 4 + 2] = excl + i2;
        scn[t * 4 + 3] = excl + i3;
    }
    __syncthreads();
    cur[t] = scn[t] - h[t];
    __syncthreads();
    int cnt_local = scn[255];
    for (int i = t; i < CHUNK; i += 256) {
        int e = e0 + i;
        if (e < N_EDGES) {
            int d = dst[e];
            int b = d >> 9;
            int p = atomicAdd(&cur[b], 1);
            pl[p] = src[e] | ((d & 511) << 17);
            bb[p] = (unsigned char)b;
        }
    }
    __syncthreads();
    if (h[t] > 0) gb[t] = atomicAdd(&gcur[t], h[t]);
    __syncthreads();
    for (int i = t; i < cnt_local; i += 256) {
        int b = bb[i];
        int pos = gb[b] + (i - (scn[b] - h[b]));
        if (pos < (b + 1) * BCAP) pk[pos] = pl[i];
    }
}

// Per bucket: LDS deg-hist -> wave scan -> scatter -> sequential csr + ranges.
__global__ __launch_bounds__(512) void csr_build(
    const int* __restrict__ gcur, const int* __restrict__ pk,
    int* __restrict__ csr, int2* __restrict__ node_range)
{
    __shared__ int deg[512], scn[512], cur[512];
    __shared__ int csr_l[BCAP];
    int t = threadIdx.x;
    int b = blockIdx.x;
    int base = b * BCAP;
    int cnt = gcur[b] - base;
    if (cnt > BCAP) cnt = BCAP;
    deg[t] = 0;
    __syncthreads();
    for (int i = t; i < cnt; i += 512)
        atomicAdd(&deg[pk[base + i] >> 17], 1);
    __syncthreads();
    // single-wave shfl scan of 512 counts: 8 elems/lane
    if (t < 64) {
        int e[8], inc[8], s = 0;
#pragma unroll
        for (int k = 0; k < 8; k++) { e[k] = deg[t * 8 + k]; s += e[k]; inc[k] = s; }
        int run = s;
#pragma unroll
        for (int off = 1; off < 64; off <<= 1) {
            int u = __shfl_up(run, off);
            if (t >= off) run += u;
        }
        int excl = run - s;
#pragma unroll
        for (int k = 0; k < 8; k++) scn[t * 8 + k] = excl + inc[k];
    }
    __syncthreads();
    int excl = scn[t] - deg[t];
    cur[t] = excl;
    int n = (b << 9) + t;
    if (n < N_NODES) node_range[n] = make_int2(base + excl, base + excl + deg[t]);
    __syncthreads();
    for (int i = t; i < cnt; i += 512) {
        int v = pk[base + i];
        int p = atomicAdd(&cur[v >> 17], 1);
        csr_l[p] = v & 0x1FFFF;
    }
    __syncthreads();
    for (int i = t; i < cnt; i += 512)
        csr[base + i] = csr_l[i];
}

// ---- Fused layers: phase 1 gather-mean -> LDS, phase 2 MFMA ------------
// Phase 1 (8 waves x 8 nodes): R12's zero-reduction gather; mean row (64 bf16,
// 32 words) written at LDS stride MSTRIDE=36 words.
// Phase 2 (waves 0-3): verified R6 MFMA body; A-mean frags from LDS
// (lanes n16 -> addr stride 36 words -> banks {0,4..28}x2 = 2-way, free).

__device__ __forceinline__ void gather_mean_lds(
    const bf16* __restrict__ feat, const int2* __restrict__ node_range,
    const int* __restrict__ csr, int nb0, uint* __restrict__ mean_l)
{
    int wave = threadIdx.x >> 6, lane = threadIdx.x & 63;
    int g = lane >> 3, ci = lane & 7;
    int nl = wave * 8 + g;
    int n = nb0 + nl;
    int2 rg = (n < N_NODES) ? node_range[n] : make_int2(0, 0);
    int beg = rg.x, end = rg.y;
    const uint* fw = (const uint*)feat;
    float a0 = 0.f, a1 = 0.f, a2 = 0.f, a3 = 0.f;
    float a4 = 0.f, a5 = 0.f, a6 = 0.f, a7 = 0.f;
    int i = beg;
    for (; i + 3 < end; i += 4) {
        int s0 = csr[i], s1 = csr[i + 1], s2 = csr[i + 2], s3 = csr[i + 3];
        uint4 w0 = *(const uint4*)(fw + (long)s0 * 32 + ci * 4);
        uint4 w1 = *(const uint4*)(fw + (long)s1 * 32 + ci * 4);
        uint4 w2 = *(const uint4*)(fw + (long)s2 * 32 + ci * 4);
        uint4 w3 = *(const uint4*)(fw + (long)s3 * 32 + ci * 4);
        a0 += lo_bf(w0.x) + lo_bf(w1.x) + lo_bf(w2.x) + lo_bf(w3.x);
        a1 += hi_bf(w0.x) + hi_bf(w1.x) + hi_bf(w2.x) + hi_bf(w3.x);
        a2 += lo_bf(w0.y) + lo_bf(w1.y) + lo_bf(w2.y) + lo_bf(w3.y);
        a3 += hi_bf(w0.y) + hi_bf(w1.y) + hi_bf(w2.y) + hi_bf(w3.y);
        a4 += lo_bf(w0.z) + lo_bf(w1.z) + lo_bf(w2.z) + lo_bf(w3.z);
        a5 += hi_bf(w0.z) + hi_bf(w1.z) + hi_bf(w2.z) + hi_bf(w3.z);
        a6 += lo_bf(w0.w) + lo_bf(w1.w) + lo_bf(w2.w) + lo_bf(w3.w);
        a7 += hi_bf(w0.w) + hi_bf(w1.w) + hi_bf(w2.w) + hi_bf(w3.w);
    }
    for (; i < end; i++) {
        int s = csr[i];
        uint4 w = *(const uint4*)(fw + (long)s * 32 + ci * 4);
        a0 += lo_bf(w.x); a1 += hi_bf(w.x);
        a2 += lo_bf(w.y); a3 += hi_bf(w.y);
        a4 += lo_bf(w.z); a5 += hi_bf(w.z);
        a6 += lo_bf(w.w); a7 += hi_bf(w.w);
    }
    int d = end - beg;
    float inv = d > 0 ? 1.0f / (float)d : 0.0f;
    uint4 q;
    q.x = pack2(a0 * inv, a1 * inv);
    q.y = pack2(a2 * inv, a3 * inv);
    q.z = pack2(a4 * inv, a5 * inv);
    q.w = pack2(a6 * inv, a7 * inv);
    *(uint4*)(mean_l + nl * MSTRIDE + ci * 4) = q;
}

// wlb = [Wl | Wr] bf16, each 4096
__device__ __forceinline__ short8 load_bfrag(
    const bf16* __restrict__ wlb, int f, int c, int quad)
{
    if (c < 2) return load8bf(wlb, (long)f * 64 + c * 32 + quad * 8);
    return load8bf(wlb, 4096 + (long)f * 64 + (c - 2) * 32 + quad * 8);
}

__global__ __launch_bounds__(512) void layer1_fused(
    const bf16* __restrict__ xb, const int2* __restrict__ nrng,
    const int* __restrict__ csr, const bf16* __restrict__ wlb,
    const float* __restrict__ bl, bf16* __restrict__ h_out)
{
    __shared__ uint mean_l[64 * MSTRIDE];
    int nb0 = blockIdx.x * 64;
    gather_mean_lds(xb, nrng, csr, nb0, mean_l);
    __syncthreads();
    int tid = threadIdx.x;
    int wave = tid >> 6, lane = tid & 63;
    if (wave >= 4) return;
    int quad = lane >> 4, n16 = lane & 15;
    int nb = nb0 + wave * 16;
    int ln = wave * 16 + n16;

    int node_a = nb + n16;
    int na = node_a < N_NODES ? node_a : N_NODES - 1;
    short8 a[4];
#pragma unroll
    for (int c = 0; c < 2; c++)
        a[c] = *(const short8*)(mean_l + ln * MSTRIDE + c * 16 + quad * 4);
#pragma unroll
    for (int c = 0; c < 2; c++)
        a[2 + c] = load8bf(xb, (long)na * 64 + c * 32 + quad * 8);

#pragma unroll
    for (int t = 0; t < 4; t++) {
        int f = 16 * t + n16;
        f32x4 acc = {0.f, 0.f, 0.f, 0.f};
#pragma unroll
        for (int c = 0; c < 4; c++) {
            short8 b = load_bfrag(wlb, f, c, quad);
            acc = __builtin_amdgcn_mfma_f32_16x16x32_bf16(a[c], b, acc, 0, 0, 0);
        }
        float bias = bl[f];
#pragma unroll
        for (int r = 0; r < 4; r++) {
            int node = nb + quad * 4 + r;
            if (node < N_NODES)
                h_out[(long)node * 64 + f] = __float2bfloat16(fmaxf(acc[r] + bias, 0.0f));
        }
    }
}

__global__ __launch_bounds__(512) void layer2_fused(
    const bf16* __restrict__ h1, const int2* __restrict__ nrng,
    const int* __restrict__ csr, const bf16* __restrict__ wlb,
    const float* __restrict__ bl, const float* __restrict__ Wlin,
    float* __restrict__ s_src, float* __restrict__ s_dst)
{
    __shared__ uint mean_l[64 * MSTRIDE];
    int nb0 = blockIdx.x * 64;
    gather_mean_lds(h1, nrng, csr, nb0, mean_l);
    __syncthreads();
    int tid = threadIdx.x;
    int wave = tid >> 6, lane = tid & 63;
    if (wave >= 4) return;
    int quad = lane >> 4, n16 = lane & 15;
    int nb = nb0 + wave * 16;
    int ln = wave * 16 + n16;

    int node_a = nb + n16;
    int na = node_a < N_NODES ? node_a : N_NODES - 1;
    short8 a[4];
#pragma unroll
    for (int c = 0; c < 2; c++)
        a[c] = *(const short8*)(mean_l + ln * MSTRIDE + c * 16 + quad * 4);
#pragma unroll
    for (int c = 0; c < 2; c++)
        a[2 + c] = load8bf(h1, (long)na * 64 + c * 32 + quad * 8);

    float sa[4] = {0.f, 0.f, 0.f, 0.f};
    float sb[4] = {0.f, 0.f, 0.f, 0.f};
#pragma unroll
    for (int t = 0; t < 4; t++) {
        int f = 16 * t + n16;
        f32x4 acc = {0.f, 0.f, 0.f, 0.f};
#pragma unroll
        for (int c = 0; c < 4; c++) {
            short8 b = load_bfrag(wlb, f, c, quad);
            acc = __builtin_amdgcn_mfma_f32_16x16x32_bf16(a[c], b, acc, 0, 0, 0);
        }
        float bias = bl[f];
        float wa = Wlin[f];
        float wb = Wlin[64 + f];
#pragma unroll
        for (int r = 0; r < 4; r++) {
            float h = fmaxf(acc[r] + bias, 0.0f);
            sa[r] += h * wa;
            sb[r] += h * wb;
        }
    }
#pragma unroll
    for (int m = 1; m < 16; m <<= 1) {
#pragma unroll
        for (int r = 0; r < 4; r++) {
            sa[r] += __shfl_xor(sa[r], m);
            sb[r] += __shfl_xor(sb[r], m);
        }
    }
    if (n16 == 0) {
#pragma unroll
        for (int r = 0; r < 4; r++) {
            int node = nb + quad * 4 + r;
            if (node < N_NODES) { s_src[node] = sa[r]; s_dst[node] = sb[r]; }
        }
    }
}

__global__ __launch_bounds__(256) void edge_out_kernel(
    const int* __restrict__ src, const int* __restrict__ dst,
    const float* __restrict__ s_src, const float* __restrict__ s_dst,
    const float* __restrict__ blin, float* __restrict__ out)
{
    int i = blockIdx.x * 256 + threadIdx.x;
    if (i >= N_EDGES / 4) return;
    int4 s4 = ((const int4*)src)[i];
    int4 d4 = ((const int4*)dst)[i];
    float b = blin[0];
    float4 o;
    o.x = s_src[s4.x] + s_dst[d4.x] + b;
    o.y = s_src[s4.y] + s_dst[d4.y] + b;
    o.z = s_src[s4.z] + s_dst[d4.z] + b;
    o.w = s_src[s4.w] + s_dst[d4.w] + b;
    ((float4*)out)[i] = o;
}

extern "C" void kernel_launch(void* const* d_in, const int* in_sizes, int n_in,
                              void* d_out, int out_size, void* d_ws, size_t ws_size,
                              hipStream_t stream) {
    const float* x    = (const float*)d_in[0];
    const int*   ei   = (const int*)d_in[1];
    const float* W1l  = (const float*)d_in[2];
    const float* b1l  = (const float*)d_in[3];
    const float* W1r  = (const float*)d_in[4];
    const float* W2l  = (const float*)d_in[5];
    const float* b2l  = (const float*)d_in[6];
    const float* W2r  = (const float*)d_in[7];
    const float* Wlin = (const float*)d_in[8];
    const float* blin = (const float*)d_in[9];
    float* out = (float*)d_out;

    const int* src = ei;
    const int* dst = ei + N_EDGES;

    // Workspace (~47 MB of 256 MiB; every byte read is written first)
    char* w = (char*)d_ws;
    bf16*  xb    = (bf16*)w;  w += (size_t)N_NODES * 64 * 2;   // 12.8 MB
    bf16*  h1    = (bf16*)w;  w += (size_t)N_NODES * 64 * 2;   // 12.8 MB
    float* ssrc  = (float*)w; w += (size_t)N_NODES * 4;
    float* sdst  = (float*)w; w += (size_t)N_NODES * 4;
    int2*  nrng  = (int2*)w;  w += (size_t)N_NODES * 8;        // 0.8 MB
    int*   gcur  = (int*)w;   w += 256 * 4;
    bf16*  wb    = (bf16*)w;  w += 16384 * 2;                  // 32 KB bf16 weights
    int*   pk    = (int*)w;   w += (size_t)NBUCK * BCAP * 4;   // 9.6 MB
    int*   csr   = (int*)w;   w += (size_t)NBUCK * BCAP * 4;   // 9.6 MB

    const int conv_blocks  = 6251;                      // 6250 x-convert + 1 weights
    const int fused_blocks = (N_NODES + 63) / 64;       // 1563
    const int eo_blocks    = (N_EDGES / 4 + 255) / 256; // 1563

    // ---- x/weights -> bf16 (+ gcur init) + bucketed CSR build ----
    convert_kernel<<<conv_blocks, 256, 0, stream>>>(x, xb, gcur, W1l, W1r, W2l, W2r, wb);
    partition_kernel<<<PART_BLOCKS, 256, 0, stream>>>(src, dst, gcur, pk);
    csr_build<<<NBUCK, 512, 0, stream>>>(gcur, pk, csr, nrng);

    // ---- Fused layers ----
    layer1_fused<<<fused_blocks, 512, 0, stream>>>(xb, nrng, csr, wb, b1l, h1);
    layer2_fused<<<fused_blocks, 512, 0, stream>>>(h1, nrng, csr, wb + 8192, b2l, Wlin, ssrc, sdst);

    // ---- Edge scores ----
    edge_out_kernel<<<eo_blocks, 256, 0, stream>>>(src, dst, ssrc, sdst, blin, out);
}